// Round 2
// baseline (560.814 us; speedup 1.0000x reference)
//
#include <hip/hip_runtime.h>

#define HH 128
#define WW 128
#define HW (HH*WW)

// ---- ws layout (float offsets), total ~28.6 MB ----
#define O_H1   0u         // (4,64,128,128) f32
#define O_H2   4194304u   // (4,32,128,128) f32
#define O_OFF2 6291456u   // (4,18,128,128) f32
#define O_OFF3 0u         // aliases h1 (dead by then)
#define O_WO2T 7471104u   // [ci][k][co] 64*9*18
#define O_W2T  7481472u   // [n][ci][co] 9*64*32
#define O_WO3T 7499904u   // [ci][k][co] 32*9*18
#define O_W3T  7505088u   // [n][ci][co] 9*32*4
#define O_BO2  7506240u
#define O_B2   7506258u
#define O_BO3  7506290u
#define O_B3   7506308u
#define O_FLAG 7506312u   // 1.0 = buffers are bf16, 0.0 = f32

typedef unsigned short u16;
typedef unsigned int   u32;

__device__ __forceinline__ float bf2f(u16 h) {
    return __uint_as_float(((u32)h) << 16);
}
__device__ __forceinline__ u16 f2bf(float f) {   // round-to-nearest-even
    u32 u = __float_as_uint(f);
    return (u16)((u + 0x7FFFu + ((u >> 16) & 1u)) >> 16);
}
__device__ __forceinline__ float ldm(const void* p, int i, bool bf) {
    return bf ? bf2f(((const u16*)p)[i]) : ((const float*)p)[i];
}

// ---- dtype detection: look at low 16 bits of x's 32-bit words ----
// bf16-packed: low half is a bf16 of N(0,1) -> exp bits 14:7 in [100,140], nonzero.
// raw f32:     low half = uniform mantissa bits -> in-range ~16% of the time.
// f32 holding bf16-rounded values: low half == 0 -> counted as f32.
__global__ void detect_dtype(const void* x, float* ws) {
    __shared__ int cnt[256];
    const u32* u = (const u32*)x;
    int t = threadIdx.x, c = 0;
    for (int k = 0; k < 2; ++k) {
        u32 w = u[t * 2 + k];
        u32 lo = w & 0xFFFFu;
        u32 e = (lo >> 7) & 0xFFu;
        if (lo != 0u && e >= 100u && e <= 140u) ++c;
    }
    cnt[t] = c;
    __syncthreads();
    for (int s = 128; s > 0; s >>= 1) {
        if (t < s) cnt[t] += cnt[t + s];
        __syncthreads();
    }
    if (t == 0) ws[O_FLAG] = (cnt[0] > 300) ? 1.f : 0.f;
}

// ---- weights -> f32, transposed so inner co-loops read contiguous ----
__global__ __launch_bounds__(256) void prep_weights(
        const void* wo2, const void* bo2, const void* w2, const void* b2,
        const void* wo3, const void* bo3, const void* w3, const void* b3,
        float* ws) {
    bool bf = ws[O_FLAG] != 0.f;
    int i = blockIdx.x * 256 + threadIdx.x;
    if (i < 10368) {                     // wo2t [ci][k][co] : 64*9*18
        int co = i % 18, k = (i / 18) % 9, ci = i / 162;
        ws[O_WO2T + i] = ldm(wo2, (co * 64 + ci) * 9 + k, bf);
    }
    if (i < 18432) {                     // w2t [n][ci][co] : 9*64*32
        int co = i % 32, ci = (i / 32) % 64, n = i / 2048;
        ws[O_W2T + i] = ldm(w2, (co * 64 + ci) * 9 + n, bf);
    }
    if (i < 5184) {                      // wo3t [ci][k][co] : 32*9*18
        int co = i % 18, k = (i / 18) % 9, ci = i / 162;
        ws[O_WO3T + i] = ldm(wo3, (co * 32 + ci) * 9 + k, bf);
    }
    if (i < 1152) {                      // w3t [n][ci][co] : 9*32*4
        int co = i % 4, ci = (i / 4) % 32, n = i / 128;
        ws[O_W3T + i] = ldm(w3, (co * 32 + ci) * 9 + n, bf);
    }
    if (i < 18) ws[O_BO2 + i] = ldm(bo2, i, bf);
    if (i < 32) ws[O_B2 + i]  = ldm(b2, i, bf);
    if (i < 18) ws[O_BO3 + i] = ldm(bo3, i, bf);
    if (i < 4)  ws[O_B3 + i]  = ldm(b3, i, bf);
}

// conv1: x (B,1,H,W) -> h1 (B,64,H,W) f32, relu, pad 1
__global__ __launch_bounds__(256) void conv1_kernel(
        const void* x, const void* w, const void* bias,
        float* out, const float* ws) {
    bool bf = ws[O_FLAG] != 0.f;
    int idx = blockIdx.x * 256 + threadIdx.x;     // covers 4*64*128*128
    int xw = idx & (WW - 1); int t = idx >> 7;
    int yh = t & (HH - 1);   t >>= 7;
    int co = t & 63;         int b = t >> 6;
    float acc = ldm(bias, co, bf);
    #pragma unroll
    for (int ky = 0; ky < 3; ++ky) {
        int yy = yh + ky - 1;
        #pragma unroll
        for (int kx = 0; kx < 3; ++kx) {
            int xx = xw + kx - 1;
            if (yy >= 0 && yy < HH && xx >= 0 && xx < WW)
                acc += ldm(w, co * 9 + ky * 3 + kx, bf) *
                       ldm(x, b * HW + yy * WW + xx, bf);
        }
    }
    out[idx] = fmaxf(acc, 0.f);
}

// 3x3 pad-1 conv cin -> 18. Thread = (pixel, ci-half); LDS reduce.
__global__ __launch_bounds__(256) void offconv_kernel(
        const float* in, const float* wt, const float* bias,
        float* out, int cin) {
    __shared__ float partial[128][19];
    int tid = threadIdx.x;
    int pix = tid & 127, s = tid >> 7;
    int idx = blockIdx.x * 128 + pix;
    int xw = idx & (WW - 1); int row = idx >> 7;
    int yh = row & (HH - 1); int b = row >> 7;
    int ch = cin >> 1;
    float acc[18];
    #pragma unroll
    for (int co = 0; co < 18; ++co) acc[co] = s ? 0.f : bias[co];
    const float* inb   = in + (b * cin + s * ch) * HW;
    const float* wbase = wt + s * ch * 162;
    for (int ci = 0; ci < ch; ++ci) {
        const float* p = inb + ci * HW;
        float v[9];
        #pragma unroll
        for (int ky = 0; ky < 3; ++ky) {
            int yy = yh + ky - 1;
            #pragma unroll
            for (int kx = 0; kx < 3; ++kx) {
                int xx = xw + kx - 1;
                v[ky * 3 + kx] = (yy >= 0 && yy < HH && xx >= 0 && xx < WW)
                                     ? p[yy * WW + xx] : 0.f;
            }
        }
        const float* wrow = wbase + ci * 162;
        #pragma unroll
        for (int k = 0; k < 9; ++k)
            #pragma unroll
            for (int co = 0; co < 18; ++co)
                acc[co] = fmaf(v[k], wrow[k * 18 + co], acc[co]);
    }
    if (s) {
        #pragma unroll
        for (int co = 0; co < 18; ++co) partial[pix][co] = acc[co];
    }
    __syncthreads();
    if (!s) {
        #pragma unroll
        for (int co = 0; co < 18; ++co)
            out[((b * 18 + co) * HH + yh) * WW + xw] = acc[co] + partial[pix][co];
    }
}

// fused deform_sample + stride-3 conv (64->32) + relu -> h2 f32
__global__ __launch_bounds__(256) void deform_mid(
        const float* feat, const float* off, const float* wt,
        const float* bias, float* out) {
    __shared__ float partial[128][33];
    int tid = threadIdx.x;
    int pix = tid & 127, s = tid >> 7;
    int idx = blockIdx.x * 128 + pix;
    int xw = idx & (WW - 1); int row = idx >> 7;
    int yh = row & (HH - 1); int b = row >> 7;
    float acc[32];
    #pragma unroll
    for (int co = 0; co < 32; ++co) acc[co] = s ? 0.f : bias[co];
    const float* offp = off + b * 18 * HW + yh * WW + xw;
    const float* fb   = feat + (b * 64 + s * 32) * HW;
    #pragma unroll
    for (int n = 0; n < 9; ++n) {
        float py = offp[n * HW]       + (float)(n / 3) - 1.f + (float)yh;
        float px = offp[(9 + n) * HW] + (float)(n % 3) - 1.f + (float)xw;
        py = fminf(fmaxf(py, 0.f), (float)(HH - 1));
        px = fminf(fmaxf(px, 0.f), (float)(WW - 1));
        float y0f = floorf(py), x0f = floorf(px);
        int y0 = (int)y0f, x0i = (int)x0f;
        int y1 = y0 + 1 < HH - 1 ? y0 + 1 : HH - 1;
        int x1 = x0i + 1 < WW - 1 ? x0i + 1 : WW - 1;
        float wy = py - y0f, wx = px - x0f;
        float w00 = (1.f - wy) * (1.f - wx), w01 = (1.f - wy) * wx;
        float w10 = wy * (1.f - wx),         w11 = wy * wx;
        int i00 = y0 * WW + x0i, i01 = y0 * WW + x1;
        int i10 = y1 * WW + x0i, i11 = y1 * WW + x1;
        const float* wrow = wt + (n * 64 + s * 32) * 32;
        #pragma unroll 4
        for (int ci = 0; ci < 32; ++ci) {
            const float* p = fb + ci * HW;
            float v = w00 * p[i00] + w01 * p[i01] + w10 * p[i10] + w11 * p[i11];
            #pragma unroll
            for (int co = 0; co < 32; ++co)
                acc[co] = fmaf(v, wrow[ci * 32 + co], acc[co]);
        }
    }
    if (s) {
        #pragma unroll
        for (int co = 0; co < 32; ++co) partial[pix][co] = acc[co];
    }
    __syncthreads();
    if (!s) {
        #pragma unroll
        for (int co = 0; co < 32; ++co)
            out[((b * 32 + co) * HH + yh) * WW + xw] =
                fmaxf(acc[co] + partial[pix][co], 0.f);
    }
}

// fused deform_sample + stride-3 conv (32->4) + pixel shuffle -> out
__global__ __launch_bounds__(256) void deform_final(
        const float* feat, const float* off, const float* wt,
        const float* bias, void* outp, const float* ws) {
    __shared__ float partial[128][5];
    bool bf = ws[O_FLAG] != 0.f;
    int tid = threadIdx.x;
    int pix = tid & 127, s = tid >> 7;
    int idx = blockIdx.x * 128 + pix;
    int xw = idx & (WW - 1); int row = idx >> 7;
    int yh = row & (HH - 1); int b = row >> 7;
    float acc[4];
    #pragma unroll
    for (int co = 0; co < 4; ++co) acc[co] = s ? 0.f : bias[co];
    const float* offp = off + b * 18 * HW + yh * WW + xw;
    const float* fb   = feat + (b * 32 + s * 16) * HW;
    #pragma unroll
    for (int n = 0; n < 9; ++n) {
        float py = offp[n * HW]       + (float)(n / 3) - 1.f + (float)yh;
        float px = offp[(9 + n) * HW] + (float)(n % 3) - 1.f + (float)xw;
        py = fminf(fmaxf(py, 0.f), (float)(HH - 1));
        px = fminf(fmaxf(px, 0.f), (float)(WW - 1));
        float y0f = floorf(py), x0f = floorf(px);
        int y0 = (int)y0f, x0i = (int)x0f;
        int y1 = y0 + 1 < HH - 1 ? y0 + 1 : HH - 1;
        int x1 = x0i + 1 < WW - 1 ? x0i + 1 : WW - 1;
        float wy = py - y0f, wx = px - x0f;
        float w00 = (1.f - wy) * (1.f - wx), w01 = (1.f - wy) * wx;
        float w10 = wy * (1.f - wx),         w11 = wy * wx;
        int i00 = y0 * WW + x0i, i01 = y0 * WW + x1;
        int i10 = y1 * WW + x0i, i11 = y1 * WW + x1;
        const float* wrow = wt + (n * 32 + s * 16) * 4;
        #pragma unroll 4
        for (int ci = 0; ci < 16; ++ci) {
            const float* p = fb + ci * HW;
            float v = w00 * p[i00] + w01 * p[i01] + w10 * p[i10] + w11 * p[i11];
            #pragma unroll
            for (int co = 0; co < 4; ++co)
                acc[co] = fmaf(v, wrow[ci * 4 + co], acc[co]);
        }
    }
    if (s) {
        #pragma unroll
        for (int co = 0; co < 4; ++co) partial[pix][co] = acc[co];
    }
    __syncthreads();
    if (!s) {
        #pragma unroll
        for (int co = 0; co < 4; ++co) acc[co] += partial[pix][co];
        // out (B,1,2H,2W): out[b][2y+co/2][2x+co%2] = acc[co]
        if (bf) {
            u32* o = (u32*)outp;   // 2 bf16 per word, row = 128 words
            u32 p0 = ((u32)f2bf(acc[1]) << 16) | (u32)f2bf(acc[0]);
            u32 p1 = ((u32)f2bf(acc[3]) << 16) | (u32)f2bf(acc[2]);
            o[(b * 2 * HH + 2 * yh)     * WW + xw] = p0;
            o[(b * 2 * HH + 2 * yh + 1) * WW + xw] = p1;
        } else {
            float* o = (float*)outp;
            int r0 = (b * 2 * HH + 2 * yh) * 2 * WW + 2 * xw;
            o[r0]              = acc[0];
            o[r0 + 1]          = acc[1];
            o[r0 + 2 * WW]     = acc[2];
            o[r0 + 2 * WW + 1] = acc[3];
        }
    }
}

extern "C" void kernel_launch(void* const* d_in, const int* in_sizes, int n_in,
                              void* d_out, int out_size, void* d_ws, size_t ws_size,
                              hipStream_t stream) {
    float* ws = (float*)d_ws;
    detect_dtype<<<1, 256, 0, stream>>>(d_in[0], ws);
    prep_weights<<<72, 256, 0, stream>>>(d_in[3], d_in[4], d_in[5], d_in[6],
                                         d_in[7], d_in[8], d_in[9], d_in[10], ws);
    conv1_kernel<<<16384, 256, 0, stream>>>(d_in[0], d_in[1], d_in[2],
                                            ws + O_H1, ws);
    offconv_kernel<<<512, 256, 0, stream>>>(ws + O_H1, ws + O_WO2T,
                                            ws + O_BO2, ws + O_OFF2, 64);
    deform_mid<<<512, 256, 0, stream>>>(ws + O_H1, ws + O_OFF2,
                                        ws + O_W2T, ws + O_B2, ws + O_H2);
    offconv_kernel<<<512, 256, 0, stream>>>(ws + O_H2, ws + O_WO3T,
                                            ws + O_BO3, ws + O_OFF3, 32);
    deform_final<<<512, 256, 0, stream>>>(ws + O_H2, ws + O_OFF3,
                                          ws + O_W3T, ws + O_B3, d_out, ws);
}

// Round 3
// 396.727 us; speedup vs baseline: 1.4136x; 1.4136x over previous
//
#include <hip/hip_runtime.h>

#define HH 128
#define WW 128
#define HW (HH*WW)

// ---- ws layout (float offsets), total ~30.03 MB ----
#define O_H1   0u         // (4,64,128,128) f32
#define O_H2   4194304u   // (4,32,128,128) f32
#define O_OFF2 6291456u   // (4,18,128,128) f32
#define O_OFF3 0u         // aliases h1 (dead by then)
#define O_WO2T 7471104u   // [ci][k][co20] 64*9*20 = 11520 (co padded 18->20)
#define O_W2T  7482624u   // [n][ci][co]   9*64*32 = 18432
#define O_WO3T 7501056u   // [ci][k][co20] 32*9*20 = 5760
#define O_W3T  7506816u   // [n][ci][co4]  9*32*4  = 1152
#define O_BO2  7507968u
#define O_B2   7507986u
#define O_BO3  7508018u
#define O_B3   7508036u
#define O_FLAG 7508040u   // 1.0 = buffers are bf16, 0.0 = f32

typedef unsigned short u16;
typedef unsigned int   u32;

__device__ __forceinline__ float bf2f(u16 h) {
    return __uint_as_float(((u32)h) << 16);
}
__device__ __forceinline__ u16 f2bf(float f) {   // round-to-nearest-even
    u32 u = __float_as_uint(f);
    return (u16)((u + 0x7FFFu + ((u >> 16) & 1u)) >> 16);
}
__device__ __forceinline__ float ldm(const void* p, int i, bool bf) {
    return bf ? bf2f(((const u16*)p)[i]) : ((const float*)p)[i];
}

// ---- dtype detection on x (see round-2 notes) ----
__global__ void detect_dtype(const void* x, float* ws) {
    __shared__ int cnt[256];
    const u32* u = (const u32*)x;
    int t = threadIdx.x, c = 0;
    for (int k = 0; k < 2; ++k) {
        u32 w = u[t * 2 + k];
        u32 lo = w & 0xFFFFu;
        u32 e = (lo >> 7) & 0xFFu;
        if (lo != 0u && e >= 100u && e <= 140u) ++c;
    }
    cnt[t] = c;
    __syncthreads();
    for (int s = 128; s > 0; s >>= 1) {
        if (t < s) cnt[t] += cnt[t + s];
        __syncthreads();
    }
    if (t == 0) ws[O_FLAG] = (cnt[0] > 300) ? 1.f : 0.f;
}

// ---- weights -> f32, transposed/padded for aligned float4 inner loops ----
__global__ __launch_bounds__(256) void prep_weights(
        const void* wo2, const void* bo2, const void* w2, const void* b2,
        const void* wo3, const void* bo3, const void* w3, const void* b3,
        float* ws) {
    bool bf = ws[O_FLAG] != 0.f;
    int i = blockIdx.x * 256 + threadIdx.x;
    if (i < 11520) {                     // wo2t [ci][k][co20]
        int co = i % 20, k = (i / 20) % 9, ci = i / 180;
        ws[O_WO2T + i] = (co < 18) ? ldm(wo2, (co * 64 + ci) * 9 + k, bf) : 0.f;
    }
    if (i < 18432) {                     // w2t [n][ci][co32]
        int co = i & 31, ci = (i >> 5) & 63, n = i / 2048;
        ws[O_W2T + i] = ldm(w2, (co * 64 + ci) * 9 + n, bf);
    }
    if (i < 5760) {                      // wo3t [ci][k][co20]
        int co = i % 20, k = (i / 20) % 9, ci = i / 180;
        ws[O_WO3T + i] = (co < 18) ? ldm(wo3, (co * 32 + ci) * 9 + k, bf) : 0.f;
    }
    if (i < 1152) {                      // w3t [n][ci][co4]
        int co = i & 3, ci = (i >> 2) & 31, n = i / 128;
        ws[O_W3T + i] = ldm(w3, (co * 32 + ci) * 9 + n, bf);
    }
    if (i < 18) ws[O_BO2 + i] = ldm(bo2, i, bf);
    if (i < 32) ws[O_B2 + i]  = ldm(b2, i, bf);
    if (i < 18) ws[O_BO3 + i] = ldm(bo3, i, bf);
    if (i < 4)  ws[O_B3 + i]  = ldm(b3, i, bf);
}

// conv1: x (B,1,H,W) -> h1 (B,64,H,W) f32, relu, pad 1. 4 co per thread.
__global__ __launch_bounds__(256) void conv1_kernel(
        const void* x, const void* w, const void* bias,
        float* __restrict__ out, const float* __restrict__ ws) {
    bool bf = ws[O_FLAG] != 0.f;
    int idx = blockIdx.x * 256 + threadIdx.x;     // 4*16*128*128 threads
    int xw = idx & 127; int t = idx >> 7;
    int yh = t & 127;   t >>= 7;
    int cg = t & 15;    int b = t >> 4;
    float xv[9];
    #pragma unroll
    for (int ky = 0; ky < 3; ++ky) {
        int yy = yh + ky - 1;
        #pragma unroll
        for (int kx = 0; kx < 3; ++kx) {
            int xx = xw + kx - 1;
            xv[ky * 3 + kx] =
                ((unsigned)yy < 128u && (unsigned)xx < 128u)
                    ? ldm(x, b * HW + yy * WW + xx, bf) : 0.f;
        }
    }
    #pragma unroll
    for (int j = 0; j < 4; ++j) {
        int co = cg * 4 + j;
        float acc = ldm(bias, co, bf);
        #pragma unroll
        for (int k = 0; k < 9; ++k)
            acc = fmaf(ldm(w, co * 9 + k, bf), xv[k], acc);
        out[((size_t)(b * 64 + co) * HH + yh) * WW + xw] = fmaxf(acc, 0.f);
    }
}

// 3x3 pad-1 conv cin -> 18, row-block LDS-staged, double-buffered.
// Block = (b,yh). Threads = 128 pix x 2 ci-halves.
__global__ __launch_bounds__(256) void offconv_kernel(
        const float* __restrict__ in, const float* __restrict__ wt,
        const float* __restrict__ bias, float* __restrict__ out, int cin) {
    __shared__ float smem[2432];      // stage 2x768 | partial 128x19 (union)
    int tid = threadIdx.x;
    int pix = tid & 127, s = tid >> 7;
    int bid = blockIdx.x;
    int yh = bid & 127, b = bid >> 7;
    int xw = pix;
    int ch = cin >> 1;

    // staging map: 768 floats = 2 halves x 3 rows x 128; tid<192 x float4
    int l0 = tid * 4;
    int half = l0 / 384;
    int row0 = (l0 % 384) >> 7, col0 = l0 & 127;
    int yr0 = yh - 1 + row0;
    bool sv0 = (tid < 192) && ((unsigned)yr0 < 128u);
    const float* sp0 = in + (size_t)(b * cin + half * ch) * HW + yr0 * WW + col0;

    float4 z4; z4.x = z4.y = z4.z = z4.w = 0.f;
    float4 a0 = sv0 ? *(const float4*)sp0 : z4;
    if (tid < 192) *(float4*)&smem[l0] = a0;
    __syncthreads();

    float acc[20];
    #pragma unroll
    for (int c = 0; c < 20; ++c) acc[c] = (!s && c < 18) ? bias[c] : 0.f;

    for (int r = 0; r < ch; ++r) {
        bool more = (r + 1) < ch;
        float4 n0 = z4;
        if (more && sv0) n0 = *(const float4*)(sp0 + (size_t)(r + 1) * HW);

        const float* L = smem + (r & 1) * 768 + s * 384;
        float v[9];
        #pragma unroll
        for (int ky = 0; ky < 3; ++ky) {
            const float* Lr = L + ky * 128 + xw;
            v[ky * 3 + 1] = Lr[0];
            v[ky * 3 + 0] = (xw > 0)   ? Lr[-1] : 0.f;
            v[ky * 3 + 2] = (xw < 127) ? Lr[1]  : 0.f;
        }
        const float* wr = wt + (size_t)(s * ch + r) * 180;
        #pragma unroll
        for (int k = 0; k < 9; ++k) {
            #pragma unroll
            for (int q = 0; q < 5; ++q) {
                float4 wv = *(const float4*)(wr + k * 20 + q * 4);
                acc[q * 4 + 0] = fmaf(v[k], wv.x, acc[q * 4 + 0]);
                acc[q * 4 + 1] = fmaf(v[k], wv.y, acc[q * 4 + 1]);
                acc[q * 4 + 2] = fmaf(v[k], wv.z, acc[q * 4 + 2]);
                acc[q * 4 + 3] = fmaf(v[k], wv.w, acc[q * 4 + 3]);
            }
        }
        if (more && tid < 192)
            *(float4*)&smem[((r + 1) & 1) * 768 + l0] = n0;
        __syncthreads();
    }

    if (s) {
        #pragma unroll
        for (int c = 0; c < 18; ++c) smem[pix * 19 + c] = acc[c];
    }
    __syncthreads();
    if (!s) {
        #pragma unroll
        for (int c = 0; c < 18; ++c)
            out[((size_t)(b * 18 + c) * HH + yh) * WW + xw] =
                acc[c] + smem[pix * 19 + c];
    }
}

// fused deform + stride-3 conv 64->32 + relu, row-block LDS-staged.
__global__ __launch_bounds__(256) void deform_mid(
        const float* __restrict__ feat, const float* __restrict__ off,
        const float* __restrict__ wt, const float* __restrict__ bias,
        float* __restrict__ out) {
    __shared__ float smem[4224];      // stage 2x1280 | partial 128x33 (union)
    int tid = threadIdx.x;
    int pix = tid & 127, s = tid >> 7;
    int bid = blockIdx.x;
    int yh = bid & 127, b = bid >> 7;
    int xw = pix;

    // ---- per-pixel sample geometry (reused for all ci) ----
    float sw0[9], sw1[9], sw2[9], sw3[9];
    int spk[9], sgb[9];
    const float* offp = off + (size_t)b * 18 * HW + yh * WW + xw;
    #pragma unroll
    for (int n = 0; n < 9; ++n) {
        float py = offp[n * HW]       + (float)(n / 3) - 1.f + (float)yh;
        float px = offp[(9 + n) * HW] + (float)(n % 3) - 1.f + (float)xw;
        py = fminf(fmaxf(py, 0.f), 127.f);
        px = fminf(fmaxf(px, 0.f), 127.f);
        float y0f = floorf(py), x0f = floorf(px);
        int y0 = (int)y0f, x0 = (int)x0f;
        int dy = (y0 < 127) ? 1 : 0;
        int dx = (x0 < 127) ? 1 : 0;
        float wy = py - y0f, wx = px - x0f;
        sw0[n] = (1.f - wy) * (1.f - wx);
        sw1[n] = (1.f - wy) * wx;
        sw2[n] = wy * (1.f - wx);
        sw3[n] = wy * wx;
        int slot = y0 - yh + 2;
        int inw = (slot >= 0 && slot + dy <= 4) ? 1 : 0;
        spk[n] = (inw ? (slot * 128 + x0) : 0) | (dx << 10) | (dy << 11) | (inw << 12);
        sgb[n] = y0 * 128 + x0;
    }

    // ---- staging map: 1280 floats = 2 halves x 5 rows x 128 ----
    int l0 = tid * 4;
    int h0 = l0 / 640;
    int row0 = (l0 % 640) >> 7, col0 = l0 & 127;
    int yr0 = yh - 2 + row0;
    bool sv0 = (unsigned)yr0 < 128u;
    const float* sp0 = feat + (size_t)(b * 64 + h0 * 32) * HW + yr0 * WW + col0;

    int l1 = 1024 + tid * 4;
    int row1 = (l1 % 640) >> 7, col1 = l1 & 127;
    int yr1 = yh - 2 + row1;
    bool sv1 = (tid < 64) && ((unsigned)yr1 < 128u);
    const float* sp1 = feat + (size_t)(b * 64 + 32) * HW + yr1 * WW + col1;

    float4 z4; z4.x = z4.y = z4.z = z4.w = 0.f;
    float4 a0 = sv0 ? *(const float4*)sp0 : z4;
    float4 a1 = sv1 ? *(const float4*)sp1 : z4;
    *(float4*)&smem[l0] = a0;
    if (tid < 64) *(float4*)&smem[l1] = a1;
    __syncthreads();

    float acc[32];
    #pragma unroll
    for (int c = 0; c < 32; ++c) acc[c] = s ? 0.f : bias[c];

    for (int r = 0; r < 32; ++r) {
        bool more = r < 31;
        float4 n0 = z4, n1 = z4;
        if (more) {
            if (sv0) n0 = *(const float4*)(sp0 + (size_t)(r + 1) * HW);
            if (sv1) n1 = *(const float4*)(sp1 + (size_t)(r + 1) * HW);
        }
        const float* L  = smem + (r & 1) * 1280 + s * 640;
        const float* fb = feat + (size_t)(b * 64 + s * 32 + r) * HW;
        #pragma unroll
        for (int n = 0; n < 9; ++n) {
            int pk = spk[n];
            int dxx = (pk >> 10) & 1;
            int dyy = ((pk >> 11) & 1) << 7;
            float v;
            if (pk & 4096) {
                int a = pk & 1023;
                v = sw0[n] * L[a] + sw1[n] * L[a + dxx] +
                    sw2[n] * L[a + dyy] + sw3[n] * L[a + dyy + dxx];
            } else {            // out-of-window fallback (general offsets)
                int g = sgb[n];
                v = sw0[n] * fb[g] + sw1[n] * fb[g + dxx] +
                    sw2[n] * fb[g + dyy] + sw3[n] * fb[g + dyy + dxx];
            }
            const float4* w4 = (const float4*)(wt + (size_t)(n * 64 + s * 32 + r) * 32);
            #pragma unroll
            for (int q = 0; q < 8; ++q) {
                float4 wv = w4[q];
                acc[q * 4 + 0] = fmaf(v, wv.x, acc[q * 4 + 0]);
                acc[q * 4 + 1] = fmaf(v, wv.y, acc[q * 4 + 1]);
                acc[q * 4 + 2] = fmaf(v, wv.z, acc[q * 4 + 2]);
                acc[q * 4 + 3] = fmaf(v, wv.w, acc[q * 4 + 3]);
            }
        }
        if (more) {
            int d = ((r + 1) & 1) * 1280;
            *(float4*)&smem[d + l0] = n0;
            if (tid < 64) *(float4*)&smem[d + l1] = n1;
        }
        __syncthreads();
    }

    if (s) {
        #pragma unroll
        for (int c = 0; c < 32; ++c) smem[pix * 33 + c] = acc[c];
    }
    __syncthreads();
    if (!s) {
        #pragma unroll
        for (int c = 0; c < 32; ++c)
            out[((size_t)(b * 32 + c) * HH + yh) * WW + xw] =
                fmaxf(acc[c] + smem[pix * 33 + c], 0.f);
    }
}

// fused deform + stride-3 conv 32->4 + pixel shuffle -> output.
__global__ __launch_bounds__(256) void deform_final(
        const float* __restrict__ feat, const float* __restrict__ off,
        const float* __restrict__ wt, const float* __restrict__ bias,
        void* __restrict__ outp, const float* __restrict__ ws) {
    __shared__ float smem[2560];      // stage 2x1280 | partial 128x5 (union)
    bool bf = ws[O_FLAG] != 0.f;
    int tid = threadIdx.x;
    int pix = tid & 127, s = tid >> 7;
    int bid = blockIdx.x;
    int yh = bid & 127, b = bid >> 7;
    int xw = pix;

    float sw0[9], sw1[9], sw2[9], sw3[9];
    int spk[9], sgb[9];
    const float* offp = off + (size_t)b * 18 * HW + yh * WW + xw;
    #pragma unroll
    for (int n = 0; n < 9; ++n) {
        float py = offp[n * HW]       + (float)(n / 3) - 1.f + (float)yh;
        float px = offp[(9 + n) * HW] + (float)(n % 3) - 1.f + (float)xw;
        py = fminf(fmaxf(py, 0.f), 127.f);
        px = fminf(fmaxf(px, 0.f), 127.f);
        float y0f = floorf(py), x0f = floorf(px);
        int y0 = (int)y0f, x0 = (int)x0f;
        int dy = (y0 < 127) ? 1 : 0;
        int dx = (x0 < 127) ? 1 : 0;
        float wy = py - y0f, wx = px - x0f;
        sw0[n] = (1.f - wy) * (1.f - wx);
        sw1[n] = (1.f - wy) * wx;
        sw2[n] = wy * (1.f - wx);
        sw3[n] = wy * wx;
        int slot = y0 - yh + 2;
        int inw = (slot >= 0 && slot + dy <= 4) ? 1 : 0;
        spk[n] = (inw ? (slot * 128 + x0) : 0) | (dx << 10) | (dy << 11) | (inw << 12);
        sgb[n] = y0 * 128 + x0;
    }

    int l0 = tid * 4;
    int h0 = l0 / 640;
    int row0 = (l0 % 640) >> 7, col0 = l0 & 127;
    int yr0 = yh - 2 + row0;
    bool sv0 = (unsigned)yr0 < 128u;
    const float* sp0 = feat + (size_t)(b * 32 + h0 * 16) * HW + yr0 * WW + col0;

    int l1 = 1024 + tid * 4;
    int row1 = (l1 % 640) >> 7, col1 = l1 & 127;
    int yr1 = yh - 2 + row1;
    bool sv1 = (tid < 64) && ((unsigned)yr1 < 128u);
    const float* sp1 = feat + (size_t)(b * 32 + 16) * HW + yr1 * WW + col1;

    float4 z4; z4.x = z4.y = z4.z = z4.w = 0.f;
    float4 a0 = sv0 ? *(const float4*)sp0 : z4;
    float4 a1 = sv1 ? *(const float4*)sp1 : z4;
    *(float4*)&smem[l0] = a0;
    if (tid < 64) *(float4*)&smem[l1] = a1;
    __syncthreads();

    float acc[4];
    #pragma unroll
    for (int c = 0; c < 4; ++c) acc[c] = s ? 0.f : bias[c];

    for (int r = 0; r < 16; ++r) {
        bool more = r < 15;
        float4 n0 = z4, n1 = z4;
        if (more) {
            if (sv0) n0 = *(const float4*)(sp0 + (size_t)(r + 1) * HW);
            if (sv1) n1 = *(const float4*)(sp1 + (size_t)(r + 1) * HW);
        }
        const float* L  = smem + (r & 1) * 1280 + s * 640;
        const float* fb = feat + (size_t)(b * 32 + s * 16 + r) * HW;
        #pragma unroll
        for (int n = 0; n < 9; ++n) {
            int pk = spk[n];
            int dxx = (pk >> 10) & 1;
            int dyy = ((pk >> 11) & 1) << 7;
            float v;
            if (pk & 4096) {
                int a = pk & 1023;
                v = sw0[n] * L[a] + sw1[n] * L[a + dxx] +
                    sw2[n] * L[a + dyy] + sw3[n] * L[a + dyy + dxx];
            } else {
                int g = sgb[n];
                v = sw0[n] * fb[g] + sw1[n] * fb[g + dxx] +
                    sw2[n] * fb[g + dyy] + sw3[n] * fb[g + dyy + dxx];
            }
            float4 wv = *(const float4*)(wt + (size_t)(n * 32 + s * 16 + r) * 4);
            acc[0] = fmaf(v, wv.x, acc[0]);
            acc[1] = fmaf(v, wv.y, acc[1]);
            acc[2] = fmaf(v, wv.z, acc[2]);
            acc[3] = fmaf(v, wv.w, acc[3]);
        }
        if (more) {
            int d = ((r + 1) & 1) * 1280;
            *(float4*)&smem[d + l0] = n0;
            if (tid < 64) *(float4*)&smem[d + l1] = n1;
        }
        __syncthreads();
    }

    if (s) {
        #pragma unroll
        for (int c = 0; c < 4; ++c) smem[pix * 5 + c] = acc[c];
    }
    __syncthreads();
    if (!s) {
        #pragma unroll
        for (int c = 0; c < 4; ++c) acc[c] += smem[pix * 5 + c];
        if (bf) {
            u32* o = (u32*)outp;   // 2 bf16 per word; out row = 128 words
            u32 p0 = ((u32)f2bf(acc[1]) << 16) | (u32)f2bf(acc[0]);
            u32 p1 = ((u32)f2bf(acc[3]) << 16) | (u32)f2bf(acc[2]);
            o[(size_t)(b * 2 * HH + 2 * yh)     * WW + xw] = p0;
            o[(size_t)(b * 2 * HH + 2 * yh + 1) * WW + xw] = p1;
        } else {
            float* o = (float*)outp;
            size_t r0 = (size_t)(b * 2 * HH + 2 * yh) * 2 * WW + 2 * xw;
            o[r0]              = acc[0];
            o[r0 + 1]          = acc[1];
            o[r0 + 2 * WW]     = acc[2];
            o[r0 + 2 * WW + 1] = acc[3];
        }
    }
}

extern "C" void kernel_launch(void* const* d_in, const int* in_sizes, int n_in,
                              void* d_out, int out_size, void* d_ws, size_t ws_size,
                              hipStream_t stream) {
    float* ws = (float*)d_ws;
    detect_dtype<<<1, 256, 0, stream>>>(d_in[0], ws);
    prep_weights<<<72, 256, 0, stream>>>(d_in[3], d_in[4], d_in[5], d_in[6],
                                         d_in[7], d_in[8], d_in[9], d_in[10], ws);
    conv1_kernel<<<4096, 256, 0, stream>>>(d_in[0], d_in[1], d_in[2],
                                           ws + O_H1, ws);
    offconv_kernel<<<512, 256, 0, stream>>>(ws + O_H1, ws + O_WO2T,
                                            ws + O_BO2, ws + O_OFF2, 64);
    deform_mid<<<512, 256, 0, stream>>>(ws + O_H1, ws + O_OFF2,
                                        ws + O_W2T, ws + O_B2, ws + O_H2);
    offconv_kernel<<<512, 256, 0, stream>>>(ws + O_H2, ws + O_WO3T,
                                            ws + O_BO3, ws + O_OFF3, 32);
    deform_final<<<512, 256, 0, stream>>>(ws + O_H2, ws + O_OFF3,
                                          ws + O_W3T, ws + O_B3, d_out, ws);
}